// Round 1
// 1350.016 us; speedup vs baseline: 1.1067x; 1.1067x over previous
//
#include <hip/hip_runtime.h>

typedef unsigned short u16;
typedef unsigned int   u32;
typedef unsigned long long u64;
typedef short bf16x8 __attribute__((ext_vector_type(8)));
typedef float f32x4  __attribute__((ext_vector_type(4)));

#define INF_F __builtin_inff()

__device__ __forceinline__ u16 f2bf(float f) {
  u32 u = __float_as_uint(f);
  return (u16)((u + 0x7FFFu + ((u >> 16) & 1u)) >> 16);   // RNE
}

// ---------------------------------------------------------------------------
// K0: entity table fp32 -> bf16 (RNE), row-major [ne][256]. n4 = ne*64.
// ---------------------------------------------------------------------------
__global__ __launch_bounds__(256) void k0_cvt(
    const float* __restrict__ src, u16* __restrict__ dst, int n4) {
  int id = blockIdx.x * 256 + threadIdx.x;
  if (id >= n4) return;
  float4 v = ((const float4*)src)[id];
  ((ushort4*)dst)[id] = make_ushort4(f2bf(v.x), f2bf(v.y), f2bf(v.z), f2bf(v.w));
}

// ---------------------------------------------------------------------------
// K1: span_max + span_repr fp32 (+ bf16 copy for MFMA prefilter).
// grid = 1024 blocks (b,s), 256 threads.
// ---------------------------------------------------------------------------
__global__ __launch_bounds__(256) void k1_span(
    const float* __restrict__ emb, const float* __restrict__ Wsp,
    const float* __restrict__ bsp,
    float* __restrict__ out0, float* __restrict__ out1,
    u16* __restrict__ spanbf) {
  __shared__ float SM[8][256];
  __shared__ float CLS[256];
  const int bid = blockIdx.x;          // b*256 + s
  const int b = bid >> 8, s = bid & 255;
  const int t = threadIdx.x;
  const float* eb = emb + (size_t)b * 65536;

  CLS[t] = eb[t];
  if (s == 0) out0[b * 256 + t] = eb[t];

  float m = eb[s * 256 + t];
  SM[0][t] = m;
  #pragma unroll
  for (int w = 1; w < 8; ++w) {
    if (s + w < 256) m = fmaxf(m, eb[(s + w) * 256 + t]);
    SM[w][t] = m;
  }
  __syncthreads();

  float cc = 0.f;
  for (int k = 0; k < 256; k += 4) {
    float4 cq = *(const float4*)&CLS[k];
    cc += cq.x * Wsp[(size_t)(256 + k + 0) * 256 + t];
    cc += cq.y * Wsp[(size_t)(256 + k + 1) * 256 + t];
    cc += cq.z * Wsp[(size_t)(256 + k + 2) * 256 + t];
    cc += cq.w * Wsp[(size_t)(256 + k + 3) * 256 + t];
  }
  float acc[8];
  const float base = bsp[t] + cc;
  #pragma unroll
  for (int w = 0; w < 8; ++w) acc[w] = base;

  for (int k = 0; k < 256; k += 4) {
    float w0 = Wsp[(size_t)(k + 0) * 256 + t];
    float w1 = Wsp[(size_t)(k + 1) * 256 + t];
    float w2 = Wsp[(size_t)(k + 2) * 256 + t];
    float w3 = Wsp[(size_t)(k + 3) * 256 + t];
    #pragma unroll
    for (int w = 0; w < 8; ++w) {
      float4 smq = *(const float4*)&SM[w][k];
      acc[w] += smq.x * w0; acc[w] += smq.y * w1;
      acc[w] += smq.z * w2; acc[w] += smq.w * w3;
    }
  }
  const float wm = Wsp[(size_t)512 * 256 + t];
  #pragma unroll
  for (int w = 0; w < 8; ++w) {
    float val = acc[w] + (float)(w + 1) * wm;
    size_t idx = ((size_t)w * 1024 + bid) * 256 + t;
    out1[idx] = val;
    spanbf[idx] = f2bf(val);
  }
}

// ---------------------------------------------------------------------------
// K2: bf16 MFMA sims prefilter + per-row top-16 via lane-parallel queues.
// grid = 512 = 64 rowgroups(128 rows) x 8 entity partitions (6250 each).
// 4 waves/block; wave wv owns rows [rg*128+wv*32, +32) as 2 resident
// A-fragment sets. 64-ent tiles staged bf16 in LDS (16B-chunk XOR swizzle),
// register-prefetched one tile ahead (T14 async-stage split).
// Producers: shfl-broadcast threshold compare + ballot-prefix queue append.
// Drain fast-path: ballot-mask union == 0 -> pure-SGPR skip (no LDS).
// Slow path: owner lane i (i<16) drains row {half*16+i}: lane-local
// replace-min into unordered 16-slot LDS state (17-padded: conflict-free).
// Exactness restored by K3 fp64 re-rank.
// ---------------------------------------------------------------------------
__global__ __launch_bounds__(256) void k2_mfma(
    const u16* __restrict__ spanbf, const u16* __restrict__ entbf, int ne,
    float* __restrict__ Rpv, int* __restrict__ Rpi) {
  __shared__ u32 Elds[8192];        // 32 KB: 64 ents x 256 bf16, swizzled
  __shared__ u64 Slot[4][32][17];   // 17 KB: per-wave per-row 16 slots (+pad)
  __shared__ u64 Q[4][16][17];      // 8.5 KB: per-half-row append queue (+pad)
  const int t = threadIdx.x, lane = t & 63, wv = t >> 6;
  const int m = lane & 15, q = lane >> 4, q4 = q * 4;
  const int rg = blockIdx.x & 63, p = blockIdx.x >> 6;
  const int psz = (ne + 7) >> 3;
  const int e_start = p * psz;
  const int e_end = min(ne, e_start + psz);
  const int rowbase = rg * 128 + wv * 32;
  const u64 gm = 0xFFFFull << (q * 16);
  const u64 lanelow = (lane == 63) ? 0x7FFFFFFFFFFFFFFFull
                                   : ((1ull << (lane + 1)) - 1) >> 1;

  #pragma unroll
  for (int j = 0; j < 8; ++j) {
    int idx = lane + 64 * j; int rw = idx >> 4, sl = idx & 15;
    Slot[wv][rw][sl] = (0xFF800000ull << 32) | 0x7FFFFFFFull;  // (-inf, MAX)
  }
  float mnv0 = -INF_F, mnv1 = -INF_F;   // owner-lane min (rows lane, 16+lane)
  int   mns0 = 0, mns1 = 0;
  float th0[4], th1[4];
  #pragma unroll
  for (int r = 0; r < 4; ++r) { th0[r] = -INF_F; th1[r] = -INF_F; }

  // A fragments resident in registers: 2 rowfrags x 8 ksteps x 8 bf16
  bf16x8 a0[8], a1[8];
  #pragma unroll
  for (int s = 0; s < 8; ++s) {
    a0[s] = *(const bf16x8*)(spanbf + (size_t)(rowbase + m) * 256 + s * 32 + q * 8);
    a1[s] = *(const bf16x8*)(spanbf + (size_t)(rowbase + 16 + m) * 256 + s * 32 + q * 8);
  }

  // --- register-prefetch staging (issue early / LDS-write late) ---
  uint4 stg[8];
  auto load_stage = [&](int tile) {
    const int ebs = e_start + (tile << 6);
    #pragma unroll
    for (int i = 0; i < 8; ++i) {
      int id = t + 256 * i; int e = id >> 5, qq = id & 31;
      int ge = ebs + e;
      uint4 v = make_uint4(0u, 0u, 0u, 0u);
      if (ge < e_end) v = *(const uint4*)((const char*)entbf + (size_t)ge * 512 + qq * 16);
      stg[i] = v;
    }
  };
  auto write_stage = [&]() {
    #pragma unroll
    for (int i = 0; i < 8; ++i) {
      int id = t + 256 * i; int e = id >> 5, qq = id & 31;
      *(uint4*)((char*)Elds + (((e << 5) | (qq ^ (e & 31))) << 4)) = stg[i];
    }
  };

  const int ntiles = (e_end - e_start + 63) >> 6;
  load_stage(0);

  for (int tile = 0; tile < ntiles; ++tile) {
    const int eb = e_start + (tile << 6);
    __syncthreads();                 // prev tile's Elds reads done
    write_stage();
    if (tile + 1 < ntiles) load_stage(tile + 1);   // in flight during compute
    __syncthreads();                 // Elds ready

    for (int c = 0; c < 4; ++c) {
      f32x4 acc0 = {0.f, 0.f, 0.f, 0.f}, acc1 = {0.f, 0.f, 0.f, 0.f};
      const int el = c * 16 + m, sw = el & 31, bc = el << 5;
      #pragma unroll
      for (int s = 0; s < 8; ++s) {
        int qq = s * 4 + q;
        bf16x8 bfr = *(const bf16x8*)((const char*)Elds + ((bc | (qq ^ sw)) << 4));
        acc0 = __builtin_amdgcn_mfma_f32_16x16x32_bf16(a0[s], bfr, acc0, 0, 0, 0);
        acc1 = __builtin_amdgcn_mfma_f32_16x16x32_bf16(a1[s], bfr, acc1, 0, 0, 0);
      }
      const int gent = eb + c * 16 + m;
      const bool valid = gent < e_end;

      // produce: ballot hits; append to per-row queue; export full masks.
      auto produce = [&](const f32x4& av, const float* th, u64* M) {
        #pragma unroll
        for (int r = 0; r < 4; ++r) {
          bool hr = valid && (av[r] > th[r]);
          u64 br = __ballot(hr);
          M[r] = br;
          if (hr) {
            u64 mr = br & gm;
            int rq = q4 + r;
            int pos = (int)__popcll(mr & lanelow);
            Q[wv][rq][pos] = ((u64)__float_as_uint(av[r]) << 32) | (u32)gent;
          }
        }
      };
      // drain: wave-uniform SGPR skip when no hits anywhere.
      auto drain = [&](int half, const u64* M, float& mnv, int& mns) {
        if (!(M[0] | M[1] | M[2] | M[3])) return;
        if (lane < 16) {
          u64 msel = (lane & 2) ? ((lane & 1) ? M[3] : M[2])
                                : ((lane & 1) ? M[1] : M[0]);
          int cnt = (int)__popcll((msel >> ((lane >> 2) << 4)) & 0xFFFFull);
          if (cnt > 0) {
            int rw = half * 16 + lane;
            for (int i = 0; i < cnt; ++i) {
              u64 e = Q[wv][lane][i];
              float v = __uint_as_float((u32)(e >> 32));
              if (v > mnv) {
                Slot[wv][rw][mns] = e;
                float mv = INF_F; int ms2 = 0;
                #pragma unroll
                for (int s2 = 0; s2 < 16; ++s2) {
                  u64 sv = Slot[wv][rw][s2];
                  float f = __uint_as_float((u32)(sv >> 32));
                  if (f < mv) { mv = f; ms2 = s2; }
                }
                mnv = mv; mns = ms2;
              }
            }
          }
        }
      };

      u64 M0[4], M1[4];
      produce(acc0, th0, M0);
      drain(0, M0, mnv0, mns0);
      produce(acc1, th1, M1);
      drain(1, M1, mnv1, mns1);
      // refresh producer thresholds from owner-lane registers (only when
      // something drained; shfl is wave-uniform here).
      if ((M0[0] | M0[1] | M0[2] | M0[3] | M1[0] | M1[1] | M1[2] | M1[3])) {
        #pragma unroll
        for (int r = 0; r < 4; ++r) {
          th0[r] = __shfl(mnv0, q4 + r);
          th1[r] = __shfl(mnv1, q4 + r);
        }
      }
    }
  }

  if (lane < 16) {
    #pragma unroll
    for (int h = 0; h < 2; ++h) {
      int rw = h * 16 + lane;
      int row = rowbase + rw;
      for (int s = 0; s < 16; ++s) {
        u64 e = Slot[wv][rw][s];
        Rpv[(size_t)row * 128 + p * 16 + s] = __uint_as_float((u32)(e >> 32));
        Rpi[(size_t)row * 128 + p * 16 + s] = (int)(u32)e;
      }
    }
  }
}

// ---------------------------------------------------------------------------
// K2b: exact top-16 of the 128 partition candidates per row (rank counting).
// grid = 2048 blocks x 4 waves (1 row/wave).
// ---------------------------------------------------------------------------
__global__ __launch_bounds__(256) void k2_merge(
    const float* __restrict__ Rpv, const int* __restrict__ Rpi,
    int* __restrict__ Ridx) {
  const int t = threadIdx.x, lane = t & 63, wv = t >> 6;
  const int row = blockIdx.x * 4 + wv;
  const float va = Rpv[(size_t)row * 128 + lane];
  const int   ea = Rpi[(size_t)row * 128 + lane];
  const float vb = Rpv[(size_t)row * 128 + 64 + lane];
  const int   eb = Rpi[(size_t)row * 128 + 64 + lane];
  int ca = 0, cb = 0;
  for (int i = 0; i < 64; ++i) {
    float ov = __shfl(va, i); int oi = __shfl(ea, i);
    ca += (ov > va || (ov == va && oi < ea));
    cb += (ov > vb || (ov == vb && oi < eb));
  }
  for (int i = 0; i < 64; ++i) {
    float ov = __shfl(vb, i); int oi = __shfl(eb, i);
    ca += (ov > va || (ov == va && oi < ea));
    cb += (ov > vb || (ov == vb && oi < eb));
  }
  if (ca < 16) Ridx[(size_t)row * 16 + ca] = ea;
  if (cb < 16) Ridx[(size_t)row * 16 + cb] = eb;
}

// ---------------------------------------------------------------------------
// K3: recompute span row fp64, exact re-rank of 16 candidates -> ordered
// top-8, then 2-layer star-GCN (fp32). grid = 8192 blocks, 256 threads.
// ---------------------------------------------------------------------------
__global__ __launch_bounds__(256) void k3_gcn(
    const float* __restrict__ emb, const float* __restrict__ Wsp,
    const float* __restrict__ bsp, const float* __restrict__ ent,
    const int* __restrict__ Ridx,
    const float* __restrict__ W1, const float* __restrict__ b1,
    const float* __restrict__ W2, const float* __restrict__ b2,
    float* __restrict__ out2, int ne) {
  __shared__ float  SMx[256];
  __shared__ float  CLS[256];
  __shared__ double SPN[256];
  __shared__ float  Xc[16][256];
  __shared__ float  Mm[8][256];
  __shared__ double dpart[16][16];
  __shared__ double dval[16];
  __shared__ int    cidx[16];
  __shared__ int    order[8];
  const int n = blockIdx.x;
  const int t = threadIdx.x;
  const int w = n >> 10, b = (n >> 8) & 3, s = n & 255;
  const float* eb = emb + (size_t)b * 65536;

  CLS[t] = eb[t];
  float m = eb[s * 256 + t];
  for (int j = 1; j <= w; ++j)
    if (s + j < 256) m = fmaxf(m, eb[(s + j) * 256 + t]);
  SMx[t] = m;
  if (t < 16) {
    int c = Ridx[(size_t)n * 16 + t];
    if ((unsigned)c >= (unsigned)ne) c = 0;   // defensive
    cidx[t] = c;
  }
  __syncthreads();

  double a = (double)bsp[t];
  for (int k = 0; k < 256; k += 4) {
    a += (double)SMx[k + 0] * (double)Wsp[(size_t)(k + 0) * 256 + t];
    a += (double)SMx[k + 1] * (double)Wsp[(size_t)(k + 1) * 256 + t];
    a += (double)SMx[k + 2] * (double)Wsp[(size_t)(k + 2) * 256 + t];
    a += (double)SMx[k + 3] * (double)Wsp[(size_t)(k + 3) * 256 + t];
  }
  for (int k = 0; k < 256; k += 4) {
    a += (double)CLS[k + 0] * (double)Wsp[(size_t)(256 + k + 0) * 256 + t];
    a += (double)CLS[k + 1] * (double)Wsp[(size_t)(256 + k + 1) * 256 + t];
    a += (double)CLS[k + 2] * (double)Wsp[(size_t)(256 + k + 2) * 256 + t];
    a += (double)CLS[k + 3] * (double)Wsp[(size_t)(256 + k + 3) * 256 + t];
  }
  a += (double)(w + 1) * (double)Wsp[(size_t)512 * 256 + t];
  SPN[t] = a;
  __syncthreads();

  const int jr = t >> 4;
  const int kb = (t & 15) * 16;
  float x[16];
  {
    const float4* src = (const float4*)(ent + (size_t)cidx[jr] * 256 + kb);
    float4 v0 = src[0], v1 = src[1], v2 = src[2], v3 = src[3];
    x[0]=v0.x; x[1]=v0.y; x[2]=v0.z; x[3]=v0.w;
    x[4]=v1.x; x[5]=v1.y; x[6]=v1.z; x[7]=v1.w;
    x[8]=v2.x; x[9]=v2.y; x[10]=v2.z; x[11]=v2.w;
    x[12]=v3.x; x[13]=v3.y; x[14]=v3.z; x[15]=v3.w;
    #pragma unroll
    for (int qq = 0; qq < 16; ++qq) Xc[jr][kb + qq] = x[qq];
  }
  double pp = 0.0;
  #pragma unroll
  for (int kk = 0; kk < 16; ++kk) pp += (double)x[kk] * SPN[kb + kk];
  dpart[jr][t & 15] = pp;
  __syncthreads();
  if (t < 16) {
    double sacc = 0.0;
    for (int qq = 0; qq < 16; ++qq) sacc += dpart[t][qq];
    dval[t] = sacc;
  }
  __syncthreads();
  if (t == 0) {
    unsigned used = 0;
    for (int o = 0; o < 8; ++o) {
      int best = -1; double bv = 0.0; int bi = 0;
      for (int j = 0; j < 16; ++j) {
        if (used & (1u << j)) continue;
        if (best < 0 || dval[j] > bv || (dval[j] == bv && cidx[j] < bi)) {
          best = j; bv = dval[j]; bi = cidx[j];
        }
      }
      used |= (1u << best);
      order[o] = best;
    }
  }
  __syncthreads();

  {
    float x0 = Xc[order[0]][t];
    float xs[7]; float ssum = 0.f;
    #pragma unroll
    for (int j = 1; j < 8; ++j) { xs[j - 1] = Xc[order[j]][t]; ssum += xs[j - 1]; }
    Mm[0][t] = x0 * 0.125f + ssum * 0.25f;
    #pragma unroll
    for (int j = 1; j < 8; ++j) Mm[j][t] = x0 * 0.25f + xs[j - 1] * 0.5f;
  }
  __syncthreads();

  float acc[8];
  {
    float bbv = b1[t];
    #pragma unroll
    for (int r = 0; r < 8; ++r) acc[r] = bbv;
    for (int k = 0; k < 256; k += 4) {
      float w0 = W1[(size_t)(k + 0) * 256 + t];
      float w1 = W1[(size_t)(k + 1) * 256 + t];
      float w2 = W1[(size_t)(k + 2) * 256 + t];
      float w3 = W1[(size_t)(k + 3) * 256 + t];
      #pragma unroll
      for (int r = 0; r < 8; ++r) {
        float4 mq = *(const float4*)&Mm[r][k];
        acc[r] += mq.x * w0; acc[r] += mq.y * w1;
        acc[r] += mq.z * w2; acc[r] += mq.w * w3;
      }
    }
  }
  #pragma unroll
  for (int r = 0; r < 8; ++r) Xc[r][t] = fmaxf(acc[r], 0.f);
  __syncthreads();

  {
    float y0 = Xc[0][t];
    float ys[7]; float ss = 0.f;
    #pragma unroll
    for (int j = 1; j < 8; ++j) { ys[j - 1] = Xc[j][t]; ss += ys[j - 1]; }
    float m0 = y0 * 0.125f + ss * 0.25f;
    float mj[7];
    #pragma unroll
    for (int j = 1; j < 8; ++j) mj[j - 1] = y0 * 0.25f + ys[j - 1] * 0.5f;
    Mm[0][t] = m0;
    #pragma unroll
    for (int j = 1; j < 8; ++j) Mm[j][t] = mj[j - 1];
  }
  __syncthreads();

  {
    float bbv = b2[t];
    #pragma unroll
    for (int r = 0; r < 8; ++r) acc[r] = bbv;
    for (int k = 0; k < 256; k += 4) {
      float w0 = W2[(size_t)(k + 0) * 256 + t];
      float w1 = W2[(size_t)(k + 1) * 256 + t];
      float w2 = W2[(size_t)(k + 2) * 256 + t];
      float w3 = W2[(size_t)(k + 3) * 256 + t];
      #pragma unroll
      for (int r = 0; r < 8; ++r) {
        float4 mq = *(const float4*)&Mm[r][k];
        acc[r] += mq.x * w0; acc[r] += mq.y * w1;
        acc[r] += mq.z * w2; acc[r] += mq.w * w3;
      }
    }
  }
  float* ob = out2 + (size_t)n * 2048 + t;
  #pragma unroll
  for (int r = 0; r < 8; ++r) ob[(size_t)r * 256] = acc[r];
}

// ---------------------------------------------------------------------------
extern "C" void kernel_launch(void* const* d_in, const int* in_sizes, int n_in,
                              void* d_out, int out_size, void* d_ws, size_t ws_size,
                              hipStream_t stream) {
  const float* emb = (const float*)d_in[0];
  const float* ent = (const float*)d_in[1];
  const float* Wsp = (const float*)d_in[2];
  const float* bsp = (const float*)d_in[3];
  const float* W1  = (const float*)d_in[4];
  const float* b1  = (const float*)d_in[5];
  const float* W2  = (const float*)d_in[6];
  const float* b2  = (const float*)d_in[7];
  const int ne = in_sizes[1] / 256;   // 50000

  float* out  = (float*)d_out;
  float* out0 = out;                        // cls: 1024
  float* out1 = out + 1024;                 // span_repr: 8192*256
  float* out2 = out + 1024 + 2097152;       // subgraph_out: 64 MB region

  // scratch overlays on out2 (consumed before k3 overwrites; strict order):
  char* ov = (char*)out2;
  u16*   entbf  = (u16*)(ov);                     // 25.6 MB bf16 entity table
  u16*   spanbf = (u16*)(ov + 33554432);          //  4 MB bf16 span matrix
  float* Rpv    = (float*)(ov + 41943040);        //  4 MB partial topk vals
  int*   Rpi    = (int*)  (ov + 50331648);        //  4 MB partial topk idx
  int*   Ridx   = (int*)d_ws;                     // 512 KB final top-16 idx

  hipLaunchKernelGGL(k0_cvt, dim3((ne * 64 + 255) / 256), dim3(256), 0, stream,
                     ent, entbf, ne * 64);
  hipLaunchKernelGGL(k1_span, dim3(1024), dim3(256), 0, stream,
                     emb, Wsp, bsp, out0, out1, spanbf);
  hipLaunchKernelGGL(k2_mfma, dim3(512), dim3(256), 0, stream,
                     spanbf, entbf, ne, Rpv, Rpi);
  hipLaunchKernelGGL(k2_merge, dim3(2048), dim3(256), 0, stream,
                     Rpv, Rpi, Ridx);
  hipLaunchKernelGGL(k3_gcn, dim3(8192), dim3(256), 0, stream,
                     emb, Wsp, bsp, ent, Ridx, W1, b1, W2, b2, out2, ne);
}

// Round 2
// 1096.208 us; speedup vs baseline: 1.3629x; 1.2315x over previous
//
#include <hip/hip_runtime.h>

typedef unsigned short u16;
typedef unsigned int   u32;
typedef unsigned long long u64;
typedef short bf16x8 __attribute__((ext_vector_type(8)));
typedef float f32x4  __attribute__((ext_vector_type(4)));

#define INF_F __builtin_inff()

__device__ __forceinline__ u16 f2bf(float f) {
  u32 u = __float_as_uint(f);
  return (u16)((u + 0x7FFFu + ((u >> 16) & 1u)) >> 16);   // RNE
}

// float -> monotonic-sortable u32 (bigger = larger float)
__device__ __forceinline__ u32 sortf(float f) {
  u32 u = __float_as_uint(f);
  return u ^ ((u32)((int)u >> 31) | 0x80000000u);
}
__device__ __forceinline__ float unsortf(u32 s) {
  u32 u = s ^ ((s & 0x80000000u) ? 0x80000000u : 0xFFFFFFFFu);
  return __uint_as_float(u);
}
__device__ __forceinline__ u64 sx64(u64 v, int m) {
  u32 lo = __shfl_xor((u32)v, m);
  u32 hi = __shfl_xor((u32)(v >> 32), m);
  return ((u64)hi << 32) | lo;
}

// ---------------------------------------------------------------------------
// K0: entity table fp32 -> bf16 (RNE), row-major [ne][256]. n4 = ne*64.
// ---------------------------------------------------------------------------
__global__ __launch_bounds__(256) void k0_cvt(
    const float* __restrict__ src, u16* __restrict__ dst, int n4) {
  int id = blockIdx.x * 256 + threadIdx.x;
  if (id >= n4) return;
  float4 v = ((const float4*)src)[id];
  ((ushort4*)dst)[id] = make_ushort4(f2bf(v.x), f2bf(v.y), f2bf(v.z), f2bf(v.w));
}

// ---------------------------------------------------------------------------
// K1: span_max + span_repr fp32 (+ bf16 copy for MFMA prefilter).
// grid = 1024 blocks (b,s), 256 threads.
// ---------------------------------------------------------------------------
__global__ __launch_bounds__(256) void k1_span(
    const float* __restrict__ emb, const float* __restrict__ Wsp,
    const float* __restrict__ bsp,
    float* __restrict__ out0, float* __restrict__ out1,
    u16* __restrict__ spanbf) {
  __shared__ float SM[8][256];
  __shared__ float CLS[256];
  const int bid = blockIdx.x;          // b*256 + s
  const int b = bid >> 8, s = bid & 255;
  const int t = threadIdx.x;
  const float* eb = emb + (size_t)b * 65536;

  CLS[t] = eb[t];
  if (s == 0) out0[b * 256 + t] = eb[t];

  float m = eb[s * 256 + t];
  SM[0][t] = m;
  #pragma unroll
  for (int w = 1; w < 8; ++w) {
    if (s + w < 256) m = fmaxf(m, eb[(s + w) * 256 + t]);
    SM[w][t] = m;
  }
  __syncthreads();

  float cc = 0.f;
  for (int k = 0; k < 256; k += 4) {
    float4 cq = *(const float4*)&CLS[k];
    cc += cq.x * Wsp[(size_t)(256 + k + 0) * 256 + t];
    cc += cq.y * Wsp[(size_t)(256 + k + 1) * 256 + t];
    cc += cq.z * Wsp[(size_t)(256 + k + 2) * 256 + t];
    cc += cq.w * Wsp[(size_t)(256 + k + 3) * 256 + t];
  }
  float acc[8];
  const float base = bsp[t] + cc;
  #pragma unroll
  for (int w = 0; w < 8; ++w) acc[w] = base;

  for (int k = 0; k < 256; k += 4) {
    float w0 = Wsp[(size_t)(k + 0) * 256 + t];
    float w1 = Wsp[(size_t)(k + 1) * 256 + t];
    float w2 = Wsp[(size_t)(k + 2) * 256 + t];
    float w3 = Wsp[(size_t)(k + 3) * 256 + t];
    #pragma unroll
    for (int w = 0; w < 8; ++w) {
      float4 smq = *(const float4*)&SM[w][k];
      acc[w] += smq.x * w0; acc[w] += smq.y * w1;
      acc[w] += smq.z * w2; acc[w] += smq.w * w3;
    }
  }
  const float wm = Wsp[(size_t)512 * 256 + t];
  #pragma unroll
  for (int w = 0; w < 8; ++w) {
    float val = acc[w] + (float)(w + 1) * wm;
    size_t idx = ((size_t)w * 1024 + bid) * 256 + t;
    out1[idx] = val;
    spanbf[idx] = f2bf(val);
  }
}

// ---------------------------------------------------------------------------
// K2: bf16 MFMA sims prefilter + per-row top-16, wave-parallel register slots.
// grid = 512 = 64 rowgroups(128 rows) x 8 entity partitions (6250 each).
// 4 waves/block; wave wv owns rows [rg*128+wv*32, +32) as 2 resident
// A-fragment sets. 64-ent tiles staged bf16 in LDS (16B-chunk XOR swizzle),
// register-prefetched one tile ahead.
// Top-16 slots live in REGISTERS as sortable u64 keys, distributed 4 lanes x
// 4 slots per row (lane = sg*16 + row). A drain round: all 16 rows of a half
// insert one queued candidate simultaneously: local min4 (reg) + 2x shfl_xor
// group-min + single-lane replace. Rounds = max queue depth (usually 1).
// Exactness restored by K3 fp64 re-rank.
// ---------------------------------------------------------------------------
__global__ __launch_bounds__(256) void k2_mfma(
    const u16* __restrict__ spanbf, const u16* __restrict__ entbf, int ne,
    float* __restrict__ Rpv, int* __restrict__ Rpi) {
  __shared__ u32 Elds[8192];        // 32 KB: 64 ents x 256 bf16, swizzled
  __shared__ u64 Q[4][16][17];      // 8.5 KB: per-half-row append queue (+pad)
  const int t = threadIdx.x, lane = t & 63, wv = t >> 6;
  const int m = lane & 15, q = lane >> 4, q4 = q * 4;
  const int rg = blockIdx.x & 63, p = blockIdx.x >> 6;
  const int psz = (ne + 7) >> 3;
  const int e_start = p * psz;
  const int e_end = min(ne, e_start + psz);
  const int rowbase = rg * 128 + wv * 32;
  const u64 gm = 0xFFFFull << (q * 16);
  const u64 lanelow = (lane == 63) ? 0x7FFFFFFFFFFFFFFFull
                                   : ((1ull << (lane + 1)) - 1) >> 1;
  const u64 gml = gm & lanelow;
  const int row = lane & 15;        // drain role: row within half

  // register-resident slots: half0/half1, 4 slots each. key = sort<<32 | ~ent
  const u64 KINIT = ((u64)sortf(-INF_F) << 32);   // -inf, ent=~0
  u64 slot0[4], slot1[4];
  #pragma unroll
  for (int s = 0; s < 4; ++s) { slot0[s] = KINIT; slot1[s] = KINIT; }
  float myth0 = -INF_F, myth1 = -INF_F;   // this lane's row current 16th value
  float th0[4], th1[4];
  #pragma unroll
  for (int r = 0; r < 4; ++r) { th0[r] = -INF_F; th1[r] = -INF_F; }

  // A fragments resident in registers: 2 rowfrags x 8 ksteps x 8 bf16
  bf16x8 a0[8], a1[8];
  #pragma unroll
  for (int s = 0; s < 8; ++s) {
    a0[s] = *(const bf16x8*)(spanbf + (size_t)(rowbase + m) * 256 + s * 32 + q * 8);
    a1[s] = *(const bf16x8*)(spanbf + (size_t)(rowbase + 16 + m) * 256 + s * 32 + q * 8);
  }

  // --- register-prefetch staging (issue early / LDS-write late) ---
  uint4 stg[8];
  auto load_stage = [&](int tile) {
    const int ebs = e_start + (tile << 6);
    #pragma unroll
    for (int i = 0; i < 8; ++i) {
      int id = t + 256 * i; int e = id >> 5, qq = id & 31;
      int ge = ebs + e;
      uint4 v = make_uint4(0u, 0u, 0u, 0u);
      if (ge < e_end) v = *(const uint4*)((const char*)entbf + (size_t)ge * 512 + qq * 16);
      stg[i] = v;
    }
  };
  auto write_stage = [&]() {
    #pragma unroll
    for (int i = 0; i < 8; ++i) {
      int id = t + 256 * i; int e = id >> 5, qq = id & 31;
      *(uint4*)((char*)Elds + (((e << 5) | (qq ^ (e & 31))) << 4)) = stg[i];
    }
  };

  const int ntiles = (e_end - e_start + 63) >> 6;
  load_stage(0);

  for (int tile = 0; tile < ntiles; ++tile) {
    const int eb = e_start + (tile << 6);
    __syncthreads();                 // prev tile's Elds reads done
    write_stage();
    if (tile + 1 < ntiles) load_stage(tile + 1);   // in flight during compute
    __syncthreads();                 // Elds ready

    for (int c = 0; c < 4; ++c) {
      f32x4 acc0 = {0.f, 0.f, 0.f, 0.f}, acc1 = {0.f, 0.f, 0.f, 0.f};
      const int el = c * 16 + m, sw = el & 31, bc = el << 5;
      #pragma unroll
      for (int s = 0; s < 8; ++s) {
        int qq = s * 4 + q;
        bf16x8 bfr = *(const bf16x8*)((const char*)Elds + ((bc | (qq ^ sw)) << 4));
        acc0 = __builtin_amdgcn_mfma_f32_16x16x32_bf16(a0[s], bfr, acc0, 0, 0, 0);
        acc1 = __builtin_amdgcn_mfma_f32_16x16x32_bf16(a1[s], bfr, acc1, 0, 0, 0);
      }
      const int gent = eb + c * 16 + m;
      const bool valid = gent < e_end;

      // produce: ballot hits; append sortable keys to per-row queue.
      auto produce = [&](const f32x4& av, const float* th, u64* M) {
        #pragma unroll
        for (int r = 0; r < 4; ++r) {
          bool hr = valid && (av[r] > th[r]);
          u64 br = __ballot(hr);
          M[r] = br;
          if (hr) {
            int pos = (int)__popcll(br & gml);
            Q[wv][q4 + r][pos] = ((u64)sortf(av[r]) << 32) | (u32)(~(u32)gent);
          }
        }
      };
      // drain: wave-parallel rounds; all 16 rows insert concurrently.
      auto drain = [&](const u64* M, u64* slot, float& myth) {
        if (!(M[0] | M[1] | M[2] | M[3])) return;
        u64 msk = (row & 2) ? ((row & 1) ? M[3] : M[2])
                            : ((row & 1) ? M[1] : M[0]);
        int cnt = (int)__popcll((msk >> ((row >> 2) << 4)) & 0xFFFFull);
        int cmax = cnt;
        #pragma unroll
        for (int o = 1; o < 16; o <<= 1)
          cmax = max(cmax, __shfl_xor(cmax, o));
        for (int j = 0; j < cmax; ++j) {
          u64 cand = Q[wv][row][j];
          if (j >= cnt) cand = 0;                    // never inserts
          u64 m01 = slot[0] < slot[1] ? slot[0] : slot[1];
          u64 m23 = slot[2] < slot[3] ? slot[2] : slot[3];
          u64 lmin = m01 < m23 ? m01 : m23;
          u64 g = sx64(lmin, 16); if (g < lmin) lmin = g;
          g = sx64(lmin, 32); u64 gmin = (g < lmin) ? g : lmin;
          bool ins = cand > gmin;
          #pragma unroll
          for (int s2 = 0; s2 < 4; ++s2)
            if (ins && slot[s2] == gmin) slot[s2] = cand;
        }
        // refresh this row's 16th value (group min) for producer thresholds
        u64 m01 = slot[0] < slot[1] ? slot[0] : slot[1];
        u64 m23 = slot[2] < slot[3] ? slot[2] : slot[3];
        u64 lmin = m01 < m23 ? m01 : m23;
        u64 g = sx64(lmin, 16); if (g < lmin) lmin = g;
        g = sx64(lmin, 32); if (g < lmin) lmin = g;
        myth = unsortf((u32)(lmin >> 32));
      };

      u64 M0[4], M1[4];
      produce(acc0, th0, M0);
      drain(M0, slot0, myth0);
      produce(acc1, th1, M1);
      drain(M1, slot1, myth1);
      if (M0[0] | M0[1] | M0[2] | M0[3]) {
        #pragma unroll
        for (int r = 0; r < 4; ++r) th0[r] = __shfl(myth0, q4 + r);
      }
      if (M1[0] | M1[1] | M1[2] | M1[3]) {
        #pragma unroll
        for (int r = 0; r < 4; ++r) th1[r] = __shfl(myth1, q4 + r);
      }
    }
  }

  // writeout: lane (sg,row) holds slots sg*4+s of rows rowbase+row (+16)
  {
    const int sg = lane >> 4;
    const int r0 = rowbase + row, r1 = rowbase + 16 + row;
    #pragma unroll
    for (int s = 0; s < 4; ++s) {
      u64 e0 = slot0[s], e1 = slot1[s];
      int col = p * 16 + sg * 4 + s;
      Rpv[(size_t)r0 * 128 + col] = unsortf((u32)(e0 >> 32));
      Rpi[(size_t)r0 * 128 + col] = (int)(~(u32)e0);
      Rpv[(size_t)r1 * 128 + col] = unsortf((u32)(e1 >> 32));
      Rpi[(size_t)r1 * 128 + col] = (int)(~(u32)e1);
    }
  }
}

// ---------------------------------------------------------------------------
// K2b: exact top-16 of the 128 partition candidates per row (rank counting).
// grid = 2048 blocks x 4 waves (1 row/wave).
// ---------------------------------------------------------------------------
__global__ __launch_bounds__(256) void k2_merge(
    const float* __restrict__ Rpv, const int* __restrict__ Rpi,
    int* __restrict__ Ridx) {
  const int t = threadIdx.x, lane = t & 63, wv = t >> 6;
  const int row = blockIdx.x * 4 + wv;
  const float va = Rpv[(size_t)row * 128 + lane];
  const int   ea = Rpi[(size_t)row * 128 + lane];
  const float vb = Rpv[(size_t)row * 128 + 64 + lane];
  const int   eb = Rpi[(size_t)row * 128 + 64 + lane];
  int ca = 0, cb = 0;
  for (int i = 0; i < 64; ++i) {
    float ov = __shfl(va, i); int oi = __shfl(ea, i);
    ca += (ov > va || (ov == va && oi < ea));
    cb += (ov > vb || (ov == vb && oi < eb));
  }
  for (int i = 0; i < 64; ++i) {
    float ov = __shfl(vb, i); int oi = __shfl(eb, i);
    ca += (ov > va || (ov == va && oi < ea));
    cb += (ov > vb || (ov == vb && oi < eb));
  }
  if (ca < 16) Ridx[(size_t)row * 16 + ca] = ea;
  if (cb < 16) Ridx[(size_t)row * 16 + cb] = eb;
}

// ---------------------------------------------------------------------------
// K3: recompute span row fp64, exact re-rank of 16 candidates -> ordered
// top-8, then 2-layer star-GCN (fp32). grid = 8192 blocks, 256 threads.
// ---------------------------------------------------------------------------
__global__ __launch_bounds__(256) void k3_gcn(
    const float* __restrict__ emb, const float* __restrict__ Wsp,
    const float* __restrict__ bsp, const float* __restrict__ ent,
    const int* __restrict__ Ridx,
    const float* __restrict__ W1, const float* __restrict__ b1,
    const float* __restrict__ W2, const float* __restrict__ b2,
    float* __restrict__ out2, int ne) {
  __shared__ float  SMx[256];
  __shared__ float  CLS[256];
  __shared__ double SPN[256];
  __shared__ float  Xc[16][256];
  __shared__ float  Mm[8][256];
  __shared__ double dpart[16][16];
  __shared__ double dval[16];
  __shared__ int    cidx[16];
  __shared__ int    order[8];
  const int n = blockIdx.x;
  const int t = threadIdx.x;
  const int w = n >> 10, b = (n >> 8) & 3, s = n & 255;
  const float* eb = emb + (size_t)b * 65536;

  CLS[t] = eb[t];
  float m = eb[s * 256 + t];
  for (int j = 1; j <= w; ++j)
    if (s + j < 256) m = fmaxf(m, eb[(s + j) * 256 + t]);
  SMx[t] = m;
  if (t < 16) {
    int c = Ridx[(size_t)n * 16 + t];
    if ((unsigned)c >= (unsigned)ne) c = 0;   // defensive
    cidx[t] = c;
  }
  __syncthreads();

  double a = (double)bsp[t];
  for (int k = 0; k < 256; k += 4) {
    a += (double)SMx[k + 0] * (double)Wsp[(size_t)(k + 0) * 256 + t];
    a += (double)SMx[k + 1] * (double)Wsp[(size_t)(k + 1) * 256 + t];
    a += (double)SMx[k + 2] * (double)Wsp[(size_t)(k + 2) * 256 + t];
    a += (double)SMx[k + 3] * (double)Wsp[(size_t)(k + 3) * 256 + t];
  }
  for (int k = 0; k < 256; k += 4) {
    a += (double)CLS[k + 0] * (double)Wsp[(size_t)(256 + k + 0) * 256 + t];
    a += (double)CLS[k + 1] * (double)Wsp[(size_t)(256 + k + 1) * 256 + t];
    a += (double)CLS[k + 2] * (double)Wsp[(size_t)(256 + k + 2) * 256 + t];
    a += (double)CLS[k + 3] * (double)Wsp[(size_t)(256 + k + 3) * 256 + t];
  }
  a += (double)(w + 1) * (double)Wsp[(size_t)512 * 256 + t];
  SPN[t] = a;
  __syncthreads();

  const int jr = t >> 4;
  const int kb = (t & 15) * 16;
  float x[16];
  {
    const float4* src = (const float4*)(ent + (size_t)cidx[jr] * 256 + kb);
    float4 v0 = src[0], v1 = src[1], v2 = src[2], v3 = src[3];
    x[0]=v0.x; x[1]=v0.y; x[2]=v0.z; x[3]=v0.w;
    x[4]=v1.x; x[5]=v1.y; x[6]=v1.z; x[7]=v1.w;
    x[8]=v2.x; x[9]=v2.y; x[10]=v2.z; x[11]=v2.w;
    x[12]=v3.x; x[13]=v3.y; x[14]=v3.z; x[15]=v3.w;
    #pragma unroll
    for (int qq = 0; qq < 16; ++qq) Xc[jr][kb + qq] = x[qq];
  }
  double pp = 0.0;
  #pragma unroll
  for (int kk = 0; kk < 16; ++kk) pp += (double)x[kk] * SPN[kb + kk];
  dpart[jr][t & 15] = pp;
  __syncthreads();
  if (t < 16) {
    double sacc = 0.0;
    for (int qq = 0; qq < 16; ++qq) sacc += dpart[t][qq];
    dval[t] = sacc;
  }
  __syncthreads();
  if (t == 0) {
    unsigned used = 0;
    for (int o = 0; o < 8; ++o) {
      int best = -1; double bv = 0.0; int bi = 0;
      for (int j = 0; j < 16; ++j) {
        if (used & (1u << j)) continue;
        if (best < 0 || dval[j] > bv || (dval[j] == bv && cidx[j] < bi)) {
          best = j; bv = dval[j]; bi = cidx[j];
        }
      }
      used |= (1u << best);
      order[o] = best;
    }
  }
  __syncthreads();

  {
    float x0 = Xc[order[0]][t];
    float xs[7]; float ssum = 0.f;
    #pragma unroll
    for (int j = 1; j < 8; ++j) { xs[j - 1] = Xc[order[j]][t]; ssum += xs[j - 1]; }
    Mm[0][t] = x0 * 0.125f + ssum * 0.25f;
    #pragma unroll
    for (int j = 1; j < 8; ++j) Mm[j][t] = x0 * 0.25f + xs[j - 1] * 0.5f;
  }
  __syncthreads();

  float acc[8];
  {
    float bbv = b1[t];
    #pragma unroll
    for (int r = 0; r < 8; ++r) acc[r] = bbv;
    for (int k = 0; k < 256; k += 4) {
      float w0 = W1[(size_t)(k + 0) * 256 + t];
      float w1 = W1[(size_t)(k + 1) * 256 + t];
      float w2 = W1[(size_t)(k + 2) * 256 + t];
      float w3 = W1[(size_t)(k + 3) * 256 + t];
      #pragma unroll
      for (int r = 0; r < 8; ++r) {
        float4 mq = *(const float4*)&Mm[r][k];
        acc[r] += mq.x * w0; acc[r] += mq.y * w1;
        acc[r] += mq.z * w2; acc[r] += mq.w * w3;
      }
    }
  }
  #pragma unroll
  for (int r = 0; r < 8; ++r) Xc[r][t] = fmaxf(acc[r], 0.f);
  __syncthreads();

  {
    float y0 = Xc[0][t];
    float ys[7]; float ss = 0.f;
    #pragma unroll
    for (int j = 1; j < 8; ++j) { ys[j - 1] = Xc[j][t]; ss += ys[j - 1]; }
    float m0 = y0 * 0.125f + ss * 0.25f;
    float mj[7];
    #pragma unroll
    for (int j = 1; j < 8; ++j) mj[j - 1] = y0 * 0.25f + ys[j - 1] * 0.5f;
    Mm[0][t] = m0;
    #pragma unroll
    for (int j = 1; j < 8; ++j) Mm[j][t] = mj[j - 1];
  }
  __syncthreads();

  {
    float bbv = b2[t];
    #pragma unroll
    for (int r = 0; r < 8; ++r) acc[r] = bbv;
    for (int k = 0; k < 256; k += 4) {
      float w0 = W2[(size_t)(k + 0) * 256 + t];
      float w1 = W2[(size_t)(k + 1) * 256 + t];
      float w2 = W2[(size_t)(k + 2) * 256 + t];
      float w3 = W2[(size_t)(k + 3) * 256 + t];
      #pragma unroll
      for (int r = 0; r < 8; ++r) {
        float4 mq = *(const float4*)&Mm[r][k];
        acc[r] += mq.x * w0; acc[r] += mq.y * w1;
        acc[r] += mq.z * w2; acc[r] += mq.w * w3;
      }
    }
  }
  float* ob = out2 + (size_t)n * 2048 + t;
  #pragma unroll
  for (int r = 0; r < 8; ++r) ob[(size_t)r * 256] = acc[r];
}

// ---------------------------------------------------------------------------
extern "C" void kernel_launch(void* const* d_in, const int* in_sizes, int n_in,
                              void* d_out, int out_size, void* d_ws, size_t ws_size,
                              hipStream_t stream) {
  const float* emb = (const float*)d_in[0];
  const float* ent = (const float*)d_in[1];
  const float* Wsp = (const float*)d_in[2];
  const float* bsp = (const float*)d_in[3];
  const float* W1  = (const float*)d_in[4];
  const float* b1  = (const float*)d_in[5];
  const float* W2  = (const float*)d_in[6];
  const float* b2  = (const float*)d_in[7];
  const int ne = in_sizes[1] / 256;   // 50000

  float* out  = (float*)d_out;
  float* out0 = out;                        // cls: 1024
  float* out1 = out + 1024;                 // span_repr: 8192*256
  float* out2 = out + 1024 + 2097152;       // subgraph_out: 64 MB region

  // scratch overlays on out2 (consumed before k3 overwrites; strict order):
  char* ov = (char*)out2;
  u16*   entbf  = (u16*)(ov);                     // 25.6 MB bf16 entity table
  u16*   spanbf = (u16*)(ov + 33554432);          //  4 MB bf16 span matrix
  float* Rpv    = (float*)(ov + 41943040);        //  4 MB partial topk vals
  int*   Rpi    = (int*)  (ov + 50331648);        //  4 MB partial topk idx
  int*   Ridx   = (int*)d_ws;                     // 512 KB final top-16 idx

  hipLaunchKernelGGL(k0_cvt, dim3((ne * 64 + 255) / 256), dim3(256), 0, stream,
                     ent, entbf, ne * 64);
  hipLaunchKernelGGL(k1_span, dim3(1024), dim3(256), 0, stream,
                     emb, Wsp, bsp, out0, out1, spanbf);
  hipLaunchKernelGGL(k2_mfma, dim3(512), dim3(256), 0, stream,
                     spanbf, entbf, ne, Rpv, Rpi);
  hipLaunchKernelGGL(k2_merge, dim3(2048), dim3(256), 0, stream,
                     Rpv, Rpi, Ridx);
  hipLaunchKernelGGL(k3_gcn, dim3(8192), dim3(256), 0, stream,
                     emb, Wsp, bsp, ent, Ridx, W1, b1, W2, b2, out2, ne);
}

// Round 3
// 1056.108 us; speedup vs baseline: 1.4146x; 1.0380x over previous
//
#include <hip/hip_runtime.h>

typedef unsigned short u16;
typedef unsigned int   u32;
typedef unsigned long long u64;
typedef short bf16x8 __attribute__((ext_vector_type(8)));
typedef float f32x4  __attribute__((ext_vector_type(4)));

#define INF_F __builtin_inff()

__device__ __forceinline__ u16 f2bf(float f) {
  u32 u = __float_as_uint(f);
  return (u16)((u + 0x7FFFu + ((u >> 16) & 1u)) >> 16);   // RNE
}

// float -> monotonic-sortable u32 (bigger = larger float)
__device__ __forceinline__ u32 sortf(float f) {
  u32 u = __float_as_uint(f);
  return u ^ ((u32)((int)u >> 31) | 0x80000000u);
}
__device__ __forceinline__ float unsortf(u32 s) {
  u32 u = s ^ ((s & 0x80000000u) ? 0x80000000u : 0xFFFFFFFFu);
  return __uint_as_float(u);
}
__device__ __forceinline__ u64 sx64(u64 v, int m) {
  u32 lo = __shfl_xor((u32)v, m);
  u32 hi = __shfl_xor((u32)(v >> 32), m);
  return ((u64)hi << 32) | lo;
}

// ---------------------------------------------------------------------------
// K0: entity table fp32 -> bf16 (RNE), row-major [ne][256]. n4 = ne*64.
// ---------------------------------------------------------------------------
__global__ __launch_bounds__(256) void k0_cvt(
    const float* __restrict__ src, u16* __restrict__ dst, int n4) {
  int id = blockIdx.x * 256 + threadIdx.x;
  if (id >= n4) return;
  float4 v = ((const float4*)src)[id];
  ((ushort4*)dst)[id] = make_ushort4(f2bf(v.x), f2bf(v.y), f2bf(v.z), f2bf(v.w));
}

// ---------------------------------------------------------------------------
// K1: span_max + span_repr fp32 (+ bf16 copy for MFMA prefilter).
// grid = 1024 blocks (b,s), 256 threads.
// ---------------------------------------------------------------------------
__global__ __launch_bounds__(256) void k1_span(
    const float* __restrict__ emb, const float* __restrict__ Wsp,
    const float* __restrict__ bsp,
    float* __restrict__ out0, float* __restrict__ out1,
    u16* __restrict__ spanbf) {
  __shared__ float SM[8][256];
  __shared__ float CLS[256];
  const int bid = blockIdx.x;          // b*256 + s
  const int b = bid >> 8, s = bid & 255;
  const int t = threadIdx.x;
  const float* eb = emb + (size_t)b * 65536;

  CLS[t] = eb[t];
  if (s == 0) out0[b * 256 + t] = eb[t];

  float m = eb[s * 256 + t];
  SM[0][t] = m;
  #pragma unroll
  for (int w = 1; w < 8; ++w) {
    if (s + w < 256) m = fmaxf(m, eb[(s + w) * 256 + t]);
    SM[w][t] = m;
  }
  __syncthreads();

  float cc = 0.f;
  for (int k = 0; k < 256; k += 4) {
    float4 cq = *(const float4*)&CLS[k];
    cc += cq.x * Wsp[(size_t)(256 + k + 0) * 256 + t];
    cc += cq.y * Wsp[(size_t)(256 + k + 1) * 256 + t];
    cc += cq.z * Wsp[(size_t)(256 + k + 2) * 256 + t];
    cc += cq.w * Wsp[(size_t)(256 + k + 3) * 256 + t];
  }
  float acc[8];
  const float base = bsp[t] + cc;
  #pragma unroll
  for (int w = 0; w < 8; ++w) acc[w] = base;

  for (int k = 0; k < 256; k += 4) {
    float w0 = Wsp[(size_t)(k + 0) * 256 + t];
    float w1 = Wsp[(size_t)(k + 1) * 256 + t];
    float w2 = Wsp[(size_t)(k + 2) * 256 + t];
    float w3 = Wsp[(size_t)(k + 3) * 256 + t];
    #pragma unroll
    for (int w = 0; w < 8; ++w) {
      float4 smq = *(const float4*)&SM[w][k];
      acc[w] += smq.x * w0; acc[w] += smq.y * w1;
      acc[w] += smq.z * w2; acc[w] += smq.w * w3;
    }
  }
  const float wm = Wsp[(size_t)512 * 256 + t];
  #pragma unroll
  for (int w = 0; w < 8; ++w) {
    float val = acc[w] + (float)(w + 1) * wm;
    size_t idx = ((size_t)w * 1024 + bid) * 256 + t;
    out1[idx] = val;
    spanbf[idx] = f2bf(val);
  }
}

// ---------------------------------------------------------------------------
// K2: bf16 MFMA sims prefilter + per-row top-16, wave-parallel register slots.
// grid = 512 = 64 rowgroups(128 rows) x 8 entity partitions (6250 each).
// Top-16 slots live in REGISTERS as sortable u64 keys, 4 lanes x 4 slots/row.
// Exactness restored by K3 fp64 re-rank.
// ---------------------------------------------------------------------------
__global__ __launch_bounds__(256) void k2_mfma(
    const u16* __restrict__ spanbf, const u16* __restrict__ entbf, int ne,
    float* __restrict__ Rpv, int* __restrict__ Rpi) {
  __shared__ u32 Elds[8192];        // 32 KB: 64 ents x 256 bf16, swizzled
  __shared__ u64 Q[4][16][17];      // 8.5 KB: per-half-row append queue (+pad)
  const int t = threadIdx.x, lane = t & 63, wv = t >> 6;
  const int m = lane & 15, q = lane >> 4, q4 = q * 4;
  const int rg = blockIdx.x & 63, p = blockIdx.x >> 6;
  const int psz = (ne + 7) >> 3;
  const int e_start = p * psz;
  const int e_end = min(ne, e_start + psz);
  const int rowbase = rg * 128 + wv * 32;
  const u64 gm = 0xFFFFull << (q * 16);
  const u64 lanelow = (lane == 63) ? 0x7FFFFFFFFFFFFFFFull
                                   : ((1ull << (lane + 1)) - 1) >> 1;
  const u64 gml = gm & lanelow;
  const int row = lane & 15;        // drain role: row within half

  // register-resident slots: half0/half1, 4 slots each. key = sort<<32 | ~ent
  const u64 KINIT = ((u64)sortf(-INF_F) << 32);   // -inf, ent=~0
  u64 slot0[4], slot1[4];
  #pragma unroll
  for (int s = 0; s < 4; ++s) { slot0[s] = KINIT; slot1[s] = KINIT; }
  float myth0 = -INF_F, myth1 = -INF_F;   // this lane's row current 16th value
  float th0[4], th1[4];
  #pragma unroll
  for (int r = 0; r < 4; ++r) { th0[r] = -INF_F; th1[r] = -INF_F; }

  // A fragments resident in registers: 2 rowfrags x 8 ksteps x 8 bf16
  bf16x8 a0[8], a1[8];
  #pragma unroll
  for (int s = 0; s < 8; ++s) {
    a0[s] = *(const bf16x8*)(spanbf + (size_t)(rowbase + m) * 256 + s * 32 + q * 8);
    a1[s] = *(const bf16x8*)(spanbf + (size_t)(rowbase + 16 + m) * 256 + s * 32 + q * 8);
  }

  // --- register-prefetch staging (issue early / LDS-write late) ---
  uint4 stg[8];
  auto load_stage = [&](int tile) {
    const int ebs = e_start + (tile << 6);
    #pragma unroll
    for (int i = 0; i < 8; ++i) {
      int id = t + 256 * i; int e = id >> 5, qq = id & 31;
      int ge = ebs + e;
      uint4 v = make_uint4(0u, 0u, 0u, 0u);
      if (ge < e_end) v = *(const uint4*)((const char*)entbf + (size_t)ge * 512 + qq * 16);
      stg[i] = v;
    }
  };
  auto write_stage = [&]() {
    #pragma unroll
    for (int i = 0; i < 8; ++i) {
      int id = t + 256 * i; int e = id >> 5, qq = id & 31;
      *(uint4*)((char*)Elds + (((e << 5) | (qq ^ (e & 31))) << 4)) = stg[i];
    }
  };

  const int ntiles = (e_end - e_start + 63) >> 6;
  load_stage(0);

  for (int tile = 0; tile < ntiles; ++tile) {
    const int eb = e_start + (tile << 6);
    __syncthreads();                 // prev tile's Elds reads done
    write_stage();
    if (tile + 1 < ntiles) load_stage(tile + 1);   // in flight during compute
    __syncthreads();                 // Elds ready

    for (int c = 0; c < 4; ++c) {
      f32x4 acc0 = {0.f, 0.f, 0.f, 0.f}, acc1 = {0.f, 0.f, 0.f, 0.f};
      const int el = c * 16 + m, sw = el & 31, bc = el << 5;
      #pragma unroll
      for (int s = 0; s < 8; ++s) {
        int qq = s * 4 + q;
        bf16x8 bfr = *(const bf16x8*)((const char*)Elds + ((bc | (qq ^ sw)) << 4));
        acc0 = __builtin_amdgcn_mfma_f32_16x16x32_bf16(a0[s], bfr, acc0, 0, 0, 0);
        acc1 = __builtin_amdgcn_mfma_f32_16x16x32_bf16(a1[s], bfr, acc1, 0, 0, 0);
      }
      const int gent = eb + c * 16 + m;
      const bool valid = gent < e_end;

      // produce: ballot hits; append sortable keys to per-row queue.
      auto produce = [&](const f32x4& av, const float* th, u64* M) {
        #pragma unroll
        for (int r = 0; r < 4; ++r) {
          bool hr = valid && (av[r] > th[r]);
          u64 br = __ballot(hr);
          M[r] = br;
          if (hr) {
            int pos = (int)__popcll(br & gml);
            Q[wv][q4 + r][pos] = ((u64)sortf(av[r]) << 32) | (u32)(~(u32)gent);
          }
        }
      };
      // drain: wave-parallel rounds; all 16 rows insert concurrently.
      auto drain = [&](const u64* M, u64* slot, float& myth) {
        if (!(M[0] | M[1] | M[2] | M[3])) return;
        u64 msk = (row & 2) ? ((row & 1) ? M[3] : M[2])
                            : ((row & 1) ? M[1] : M[0]);
        int cnt = (int)__popcll((msk >> ((row >> 2) << 4)) & 0xFFFFull);
        int cmax = cnt;
        #pragma unroll
        for (int o = 1; o < 16; o <<= 1)
          cmax = max(cmax, __shfl_xor(cmax, o));
        for (int j = 0; j < cmax; ++j) {
          u64 cand = Q[wv][row][j];
          if (j >= cnt) cand = 0;                    // never inserts
          u64 m01 = slot[0] < slot[1] ? slot[0] : slot[1];
          u64 m23 = slot[2] < slot[3] ? slot[2] : slot[3];
          u64 lmin = m01 < m23 ? m01 : m23;
          u64 g = sx64(lmin, 16); if (g < lmin) lmin = g;
          g = sx64(lmin, 32); u64 gmin = (g < lmin) ? g : lmin;
          bool ins = cand > gmin;
          #pragma unroll
          for (int s2 = 0; s2 < 4; ++s2)
            if (ins && slot[s2] == gmin) slot[s2] = cand;
        }
        // refresh this row's 16th value (group min) for producer thresholds
        u64 m01 = slot[0] < slot[1] ? slot[0] : slot[1];
        u64 m23 = slot[2] < slot[3] ? slot[2] : slot[3];
        u64 lmin = m01 < m23 ? m01 : m23;
        u64 g = sx64(lmin, 16); if (g < lmin) lmin = g;
        g = sx64(lmin, 32); if (g < lmin) lmin = g;
        myth = unsortf((u32)(lmin >> 32));
      };

      u64 M0[4], M1[4];
      produce(acc0, th0, M0);
      drain(M0, slot0, myth0);
      produce(acc1, th1, M1);
      drain(M1, slot1, myth1);
      if (M0[0] | M0[1] | M0[2] | M0[3]) {
        #pragma unroll
        for (int r = 0; r < 4; ++r) th0[r] = __shfl(myth0, q4 + r);
      }
      if (M1[0] | M1[1] | M1[2] | M1[3]) {
        #pragma unroll
        for (int r = 0; r < 4; ++r) th1[r] = __shfl(myth1, q4 + r);
      }
    }
  }

  // writeout: lane (sg,row) holds slots sg*4+s of rows rowbase+row (+16)
  {
    const int sg = lane >> 4;
    const int r0 = rowbase + row, r1 = rowbase + 16 + row;
    #pragma unroll
    for (int s = 0; s < 4; ++s) {
      u64 e0 = slot0[s], e1 = slot1[s];
      int col = p * 16 + sg * 4 + s;
      Rpv[(size_t)r0 * 128 + col] = unsortf((u32)(e0 >> 32));
      Rpi[(size_t)r0 * 128 + col] = (int)(~(u32)e0);
      Rpv[(size_t)r1 * 128 + col] = unsortf((u32)(e1 >> 32));
      Rpi[(size_t)r1 * 128 + col] = (int)(~(u32)e1);
    }
  }
}

// ---------------------------------------------------------------------------
// K2b: exact top-16 of the 128 partition candidates per row (rank counting).
// grid = 2048 blocks x 4 waves (1 row/wave).
// ---------------------------------------------------------------------------
__global__ __launch_bounds__(256) void k2_merge(
    const float* __restrict__ Rpv, const int* __restrict__ Rpi,
    int* __restrict__ Ridx) {
  const int t = threadIdx.x, lane = t & 63, wv = t >> 6;
  const int row = blockIdx.x * 4 + wv;
  const float va = Rpv[(size_t)row * 128 + lane];
  const int   ea = Rpi[(size_t)row * 128 + lane];
  const float vb = Rpv[(size_t)row * 128 + 64 + lane];
  const int   eb = Rpi[(size_t)row * 128 + 64 + lane];
  int ca = 0, cb = 0;
  for (int i = 0; i < 64; ++i) {
    float ov = __shfl(va, i); int oi = __shfl(ea, i);
    ca += (ov > va || (ov == va && oi < ea));
    cb += (ov > vb || (ov == vb && oi < eb));
  }
  for (int i = 0; i < 64; ++i) {
    float ov = __shfl(vb, i); int oi = __shfl(eb, i);
    ca += (ov > va || (ov == va && oi < ea));
    cb += (ov > vb || (ov == vb && oi < eb));
  }
  if (ca < 16) Ridx[(size_t)row * 16 + ca] = ea;
  if (cb < 16) Ridx[(size_t)row * 16 + cb] = eb;
}

// ---------------------------------------------------------------------------
// K3: batched-span GCN. grid = 2048 blocks x 256 threads; 4 spans/block
// (32 node rows). Re-rank reads span_repr fp32 from out1 (k1's exact
// values) and does fp64-accumulated dots with the 16 candidate entity rows
// -> ordered top-8. Then per block: gather 32 ent rows to LDS, A-mix in
// LDS, GEMM x2 with 32 register accumulators/thread (thread = out column),
// W1/W2 streamed once per block for all 4 spans (8x less W traffic).
// Mix-before-GEMM order matches the previous kernel's rounding path.
// ---------------------------------------------------------------------------
__global__ __launch_bounds__(256) void k3_gcn(
    const float* __restrict__ out1, const float* __restrict__ ent,
    const int* __restrict__ Ridx,
    const float* __restrict__ W1, const float* __restrict__ b1,
    const float* __restrict__ W2, const float* __restrict__ b2,
    float* __restrict__ out2, int ne) {
  __shared__ float  SPR[4][256];     // span_repr rows (4 KB)
  __shared__ float  Xn[32][256];     // node rows / h rows (32 KB)
  __shared__ float  Mm[32][256];     // mixed rows (32 KB)
  __shared__ double dpart[64][4];
  __shared__ double sims[4][16];
  __shared__ int    cidx[4][16];
  __shared__ int    chos[4][8];
  const int t = threadIdx.x;
  const int n0 = blockIdx.x * 4;

  #pragma unroll
  for (int g = 0; g < 4; ++g)
    SPR[g][t] = out1[(size_t)(n0 + g) * 256 + t];
  if (t < 64) {
    int g = t >> 4, j = t & 15;
    int c = Ridx[(size_t)(n0 + g) * 16 + j];
    if ((unsigned)c >= (unsigned)ne) c = 0;   // defensive
    cidx[g][j] = c;
  }
  __syncthreads();

  // re-rank dots: 64 (span,cand) pairs x 4 sub-threads x 64 dims, fp64 accum
  {
    const int pr = t >> 2, sub = t & 3;
    const int g = pr >> 4, j = pr & 15;
    const float* er = ent + (size_t)cidx[g][j] * 256 + sub * 64;
    const float* sr = &SPR[g][sub * 64];
    double s = 0.0;
    #pragma unroll
    for (int i = 0; i < 64; i += 4) {
      float4 e4 = *(const float4*)&er[i];
      float4 s4 = *(const float4*)&sr[i];
      s += (double)e4.x * (double)s4.x;
      s += (double)e4.y * (double)s4.y;
      s += (double)e4.z * (double)s4.z;
      s += (double)e4.w * (double)s4.w;
    }
    dpart[pr][sub] = s;
  }
  __syncthreads();
  if (t < 64) {
    int g = t >> 4, j = t & 15;
    sims[g][j] = dpart[t][0] + dpart[t][1] + dpart[t][2] + dpart[t][3];
  }
  __syncthreads();
  if (t < 4) {
    unsigned used = 0;
    for (int o = 0; o < 8; ++o) {
      int best = -1; double bv = 0.0; int bi = 0;
      for (int j = 0; j < 16; ++j) {
        if (used & (1u << j)) continue;
        if (best < 0 || sims[t][j] > bv || (sims[t][j] == bv && cidx[t][j] < bi)) {
          best = j; bv = sims[t][j]; bi = cidx[t][j];
        }
      }
      used |= (1u << best);
      chos[t][o] = cidx[t][best];
    }
  }
  __syncthreads();

  // gather 32 node rows (8 threads/row, 32 floats each)
  {
    const int r = t >> 3, sub = t & 7;
    const float4* src = (const float4*)(ent + (size_t)chos[r >> 3][r & 7] * 256 + sub * 32);
    float4* dst = (float4*)&Xn[r][sub * 32];
    #pragma unroll
    for (int i = 0; i < 8; ++i) dst[i] = src[i];
  }
  __syncthreads();

  // mix1: Mm = A_norm @ Xn (column-local; star graph)
  #pragma unroll
  for (int g = 0; g < 4; ++g) {
    float x0 = Xn[g * 8][t];
    float xs[7]; float ssum = 0.f;
    #pragma unroll
    for (int j = 1; j < 8; ++j) { xs[j - 1] = Xn[g * 8 + j][t]; ssum += xs[j - 1]; }
    Mm[g * 8][t] = x0 * 0.125f + ssum * 0.25f;
    #pragma unroll
    for (int j = 1; j < 8; ++j) Mm[g * 8 + j][t] = x0 * 0.25f + xs[j - 1] * 0.5f;
  }
  __syncthreads();

  float acc[32];
  // GEMM1: acc[r] = (Mm @ W1)[r][t]; h = relu(acc + b1) -> Xn
  {
    const float bb = b1[t];
    #pragma unroll
    for (int r = 0; r < 32; ++r) acc[r] = bb;
    for (int k = 0; k < 256; k += 4) {
      float w0 = W1[(size_t)(k + 0) * 256 + t];
      float w1 = W1[(size_t)(k + 1) * 256 + t];
      float w2 = W1[(size_t)(k + 2) * 256 + t];
      float w3 = W1[(size_t)(k + 3) * 256 + t];
      #pragma unroll
      for (int r = 0; r < 32; ++r) {
        float4 mq = *(const float4*)&Mm[r][k];
        acc[r] += mq.x * w0; acc[r] += mq.y * w1;
        acc[r] += mq.z * w2; acc[r] += mq.w * w3;
      }
    }
    #pragma unroll
    for (int r = 0; r < 32; ++r) Xn[r][t] = fmaxf(acc[r], 0.f);
  }
  __syncthreads();   // all GEMM1 reads of Mm done before mix2 overwrites

  // mix2: Mm = A_norm @ h (h in Xn; column-local, own writes)
  #pragma unroll
  for (int g = 0; g < 4; ++g) {
    float y0 = Xn[g * 8][t];
    float ys[7]; float ss = 0.f;
    #pragma unroll
    for (int j = 1; j < 8; ++j) { ys[j - 1] = Xn[g * 8 + j][t]; ss += ys[j - 1]; }
    Mm[g * 8][t] = y0 * 0.125f + ss * 0.25f;
    #pragma unroll
    for (int j = 1; j < 8; ++j) Mm[g * 8 + j][t] = y0 * 0.25f + ys[j - 1] * 0.5f;
  }
  __syncthreads();

  // GEMM2: out = Mm @ W2 + b2
  {
    const float bb = b2[t];
    #pragma unroll
    for (int r = 0; r < 32; ++r) acc[r] = bb;
    for (int k = 0; k < 256; k += 4) {
      float w0 = W2[(size_t)(k + 0) * 256 + t];
      float w1 = W2[(size_t)(k + 1) * 256 + t];
      float w2 = W2[(size_t)(k + 2) * 256 + t];
      float w3 = W2[(size_t)(k + 3) * 256 + t];
      #pragma unroll
      for (int r = 0; r < 32; ++r) {
        float4 mq = *(const float4*)&Mm[r][k];
        acc[r] += mq.x * w0; acc[r] += mq.y * w1;
        acc[r] += mq.z * w2; acc[r] += mq.w * w3;
      }
    }
    #pragma unroll
    for (int g = 0; g < 4; ++g) {
      float* ob = out2 + (size_t)(n0 + g) * 2048 + t;
      #pragma unroll
      for (int o = 0; o < 8; ++o) ob[(size_t)o * 256] = acc[g * 8 + o];
    }
  }
}

// ---------------------------------------------------------------------------
extern "C" void kernel_launch(void* const* d_in, const int* in_sizes, int n_in,
                              void* d_out, int out_size, void* d_ws, size_t ws_size,
                              hipStream_t stream) {
  const float* emb = (const float*)d_in[0];
  const float* ent = (const float*)d_in[1];
  const float* Wsp = (const float*)d_in[2];
  const float* bsp = (const float*)d_in[3];
  const float* W1  = (const float*)d_in[4];
  const float* b1  = (const float*)d_in[5];
  const float* W2  = (const float*)d_in[6];
  const float* b2  = (const float*)d_in[7];
  const int ne = in_sizes[1] / 256;   // 50000

  float* out  = (float*)d_out;
  float* out0 = out;                        // cls: 1024
  float* out1 = out + 1024;                 // span_repr: 8192*256
  float* out2 = out + 1024 + 2097152;       // subgraph_out: 64 MB region

  // scratch overlays on out2 (consumed before k3 overwrites; strict order):
  char* ov = (char*)out2;
  u16*   entbf  = (u16*)(ov);                     // 25.6 MB bf16 entity table
  u16*   spanbf = (u16*)(ov + 33554432);          //  4 MB bf16 span matrix
  float* Rpv    = (float*)(ov + 41943040);        //  4 MB partial topk vals
  int*   Rpi    = (int*)  (ov + 50331648);        //  4 MB partial topk idx
  int*   Ridx   = (int*)d_ws;                     // 512 KB final top-16 idx

  hipLaunchKernelGGL(k0_cvt, dim3((ne * 64 + 255) / 256), dim3(256), 0, stream,
                     ent, entbf, ne * 64);
  hipLaunchKernelGGL(k1_span, dim3(1024), dim3(256), 0, stream,
                     emb, Wsp, bsp, out0, out1, spanbf);
  hipLaunchKernelGGL(k2_mfma, dim3(512), dim3(256), 0, stream,
                     spanbf, entbf, ne, Rpv, Rpi);
  hipLaunchKernelGGL(k2_merge, dim3(2048), dim3(256), 0, stream,
                     Rpv, Rpi, Ridx);
  hipLaunchKernelGGL(k3_gcn, dim3(2048), dim3(256), 0, stream,
                     out1, ent, Ridx, W1, b1, W2, b2, out2, ne);
}

// Round 4
// 755.557 us; speedup vs baseline: 1.9774x; 1.3978x over previous
//
#include <hip/hip_runtime.h>

typedef unsigned short u16;
typedef unsigned int   u32;
typedef unsigned long long u64;
typedef short bf16x8 __attribute__((ext_vector_type(8)));
typedef float f32x4  __attribute__((ext_vector_type(4)));

#define INF_F __builtin_inff()

__device__ __forceinline__ u16 f2bf(float f) {
  u32 u = __float_as_uint(f);
  return (u16)((u + 0x7FFFu + ((u >> 16) & 1u)) >> 16);   // RNE
}

// float -> monotonic-sortable u32 (bigger = larger float)
__device__ __forceinline__ u32 sortf(float f) {
  u32 u = __float_as_uint(f);
  return u ^ ((u32)((int)u >> 31) | 0x80000000u);
}
__device__ __forceinline__ float unsortf(u32 s) {
  u32 u = s ^ ((s & 0x80000000u) ? 0x80000000u : 0xFFFFFFFFu);
  return __uint_as_float(u);
}
__device__ __forceinline__ u64 sx64(u64 v, int m) {
  u32 lo = __shfl_xor((u32)v, m);
  u32 hi = __shfl_xor((u32)(v >> 32), m);
  return ((u64)hi << 32) | lo;
}

// ---------------------------------------------------------------------------
// K0: entity table fp32 -> bf16 (RNE), row-major [ne][256]. n4 = ne*64.
// ---------------------------------------------------------------------------
__global__ __launch_bounds__(256) void k0_cvt(
    const float* __restrict__ src, u16* __restrict__ dst, int n4) {
  int id = blockIdx.x * 256 + threadIdx.x;
  if (id >= n4) return;
  float4 v = ((const float4*)src)[id];
  ((ushort4*)dst)[id] = make_ushort4(f2bf(v.x), f2bf(v.y), f2bf(v.z), f2bf(v.w));
}

// ---------------------------------------------------------------------------
// K1: span_max + span_repr fp32 (+ bf16 copy for MFMA prefilter).
// grid = 1024 blocks (b,s), 256 threads.
// ---------------------------------------------------------------------------
__global__ __launch_bounds__(256) void k1_span(
    const float* __restrict__ emb, const float* __restrict__ Wsp,
    const float* __restrict__ bsp,
    float* __restrict__ out0, float* __restrict__ out1,
    u16* __restrict__ spanbf) {
  __shared__ float SM[8][256];
  __shared__ float CLS[256];
  const int bid = blockIdx.x;          // b*256 + s
  const int b = bid >> 8, s = bid & 255;
  const int t = threadIdx.x;
  const float* eb = emb + (size_t)b * 65536;

  CLS[t] = eb[t];
  if (s == 0) out0[b * 256 + t] = eb[t];

  float m = eb[s * 256 + t];
  SM[0][t] = m;
  #pragma unroll
  for (int w = 1; w < 8; ++w) {
    if (s + w < 256) m = fmaxf(m, eb[(s + w) * 256 + t]);
    SM[w][t] = m;
  }
  __syncthreads();

  float cc = 0.f;
  for (int k = 0; k < 256; k += 4) {
    float4 cq = *(const float4*)&CLS[k];
    cc += cq.x * Wsp[(size_t)(256 + k + 0) * 256 + t];
    cc += cq.y * Wsp[(size_t)(256 + k + 1) * 256 + t];
    cc += cq.z * Wsp[(size_t)(256 + k + 2) * 256 + t];
    cc += cq.w * Wsp[(size_t)(256 + k + 3) * 256 + t];
  }
  float acc[8];
  const float base = bsp[t] + cc;
  #pragma unroll
  for (int w = 0; w < 8; ++w) acc[w] = base;

  for (int k = 0; k < 256; k += 4) {
    float w0 = Wsp[(size_t)(k + 0) * 256 + t];
    float w1 = Wsp[(size_t)(k + 1) * 256 + t];
    float w2 = Wsp[(size_t)(k + 2) * 256 + t];
    float w3 = Wsp[(size_t)(k + 3) * 256 + t];
    #pragma unroll
    for (int w = 0; w < 8; ++w) {
      float4 smq = *(const float4*)&SM[w][k];
      acc[w] += smq.x * w0; acc[w] += smq.y * w1;
      acc[w] += smq.z * w2; acc[w] += smq.w * w3;
    }
  }
  const float wm = Wsp[(size_t)512 * 256 + t];
  #pragma unroll
  for (int w = 0; w < 8; ++w) {
    float val = acc[w] + (float)(w + 1) * wm;
    size_t idx = ((size_t)w * 1024 + bid) * 256 + t;
    out1[idx] = val;
    spanbf[idx] = f2bf(val);
  }
}

// ---------------------------------------------------------------------------
// K2: bf16 MFMA sims prefilter + per-row top-16, wave-parallel register slots.
// grid = 512 = 64 rowgroups(128 rows) x 8 entity partitions (6250 each).
// Top-16 slots live in REGISTERS as sortable u64 keys, 4 lanes x 4 slots/row.
// Exactness restored by K3 fp64 re-rank.
// ---------------------------------------------------------------------------
__global__ __launch_bounds__(256) void k2_mfma(
    const u16* __restrict__ spanbf, const u16* __restrict__ entbf, int ne,
    float* __restrict__ Rpv, int* __restrict__ Rpi) {
  __shared__ u32 Elds[8192];        // 32 KB: 64 ents x 256 bf16, swizzled
  __shared__ u64 Q[4][16][17];      // 8.5 KB: per-half-row append queue (+pad)
  const int t = threadIdx.x, lane = t & 63, wv = t >> 6;
  const int m = lane & 15, q = lane >> 4, q4 = q * 4;
  const int rg = blockIdx.x & 63, p = blockIdx.x >> 6;
  const int psz = (ne + 7) >> 3;
  const int e_start = p * psz;
  const int e_end = min(ne, e_start + psz);
  const int rowbase = rg * 128 + wv * 32;
  const u64 gm = 0xFFFFull << (q * 16);
  const u64 lanelow = (lane == 63) ? 0x7FFFFFFFFFFFFFFFull
                                   : ((1ull << (lane + 1)) - 1) >> 1;
  const u64 gml = gm & lanelow;
  const int row = lane & 15;        // drain role: row within half

  // register-resident slots: half0/half1, 4 slots each. key = sort<<32 | ~ent
  const u64 KINIT = ((u64)sortf(-INF_F) << 32);   // -inf, ent=~0
  u64 slot0[4], slot1[4];
  #pragma unroll
  for (int s = 0; s < 4; ++s) { slot0[s] = KINIT; slot1[s] = KINIT; }
  float myth0 = -INF_F, myth1 = -INF_F;   // this lane's row current 16th value
  float th0[4], th1[4];
  #pragma unroll
  for (int r = 0; r < 4; ++r) { th0[r] = -INF_F; th1[r] = -INF_F; }

  // A fragments resident in registers: 2 rowfrags x 8 ksteps x 8 bf16
  bf16x8 a0[8], a1[8];
  #pragma unroll
  for (int s = 0; s < 8; ++s) {
    a0[s] = *(const bf16x8*)(spanbf + (size_t)(rowbase + m) * 256 + s * 32 + q * 8);
    a1[s] = *(const bf16x8*)(spanbf + (size_t)(rowbase + 16 + m) * 256 + s * 32 + q * 8);
  }

  // --- register-prefetch staging (issue early / LDS-write late) ---
  uint4 stg[8];
  auto load_stage = [&](int tile) {
    const int ebs = e_start + (tile << 6);
    #pragma unroll
    for (int i = 0; i < 8; ++i) {
      int id = t + 256 * i; int e = id >> 5, qq = id & 31;
      int ge = ebs + e;
      uint4 v = make_uint4(0u, 0u, 0u, 0u);
      if (ge < e_end) v = *(const uint4*)((const char*)entbf + (size_t)ge * 512 + qq * 16);
      stg[i] = v;
    }
  };
  auto write_stage = [&]() {
    #pragma unroll
    for (int i = 0; i < 8; ++i) {
      int id = t + 256 * i; int e = id >> 5, qq = id & 31;
      *(uint4*)((char*)Elds + (((e << 5) | (qq ^ (e & 31))) << 4)) = stg[i];
    }
  };

  const int ntiles = (e_end - e_start + 63) >> 6;
  load_stage(0);

  for (int tile = 0; tile < ntiles; ++tile) {
    const int eb = e_start + (tile << 6);
    __syncthreads();                 // prev tile's Elds reads done
    write_stage();
    if (tile + 1 < ntiles) load_stage(tile + 1);   // in flight during compute
    __syncthreads();                 // Elds ready

    for (int c = 0; c < 4; ++c) {
      f32x4 acc0 = {0.f, 0.f, 0.f, 0.f}, acc1 = {0.f, 0.f, 0.f, 0.f};
      const int el = c * 16 + m, sw = el & 31, bc = el << 5;
      #pragma unroll
      for (int s = 0; s < 8; ++s) {
        int qq = s * 4 + q;
        bf16x8 bfr = *(const bf16x8*)((const char*)Elds + ((bc | (qq ^ sw)) << 4));
        acc0 = __builtin_amdgcn_mfma_f32_16x16x32_bf16(a0[s], bfr, acc0, 0, 0, 0);
        acc1 = __builtin_amdgcn_mfma_f32_16x16x32_bf16(a1[s], bfr, acc1, 0, 0, 0);
      }
      const int gent = eb + c * 16 + m;
      const bool valid = gent < e_end;

      // produce: ballot hits; append sortable keys to per-row queue.
      auto produce = [&](const f32x4& av, const float* th, u64* M) {
        #pragma unroll
        for (int r = 0; r < 4; ++r) {
          bool hr = valid && (av[r] > th[r]);
          u64 br = __ballot(hr);
          M[r] = br;
          if (hr) {
            int pos = (int)__popcll(br & gml);
            Q[wv][q4 + r][pos] = ((u64)sortf(av[r]) << 32) | (u32)(~(u32)gent);
          }
        }
      };
      // drain: wave-parallel rounds; all 16 rows insert concurrently.
      auto drain = [&](const u64* M, u64* slot, float& myth) {
        if (!(M[0] | M[1] | M[2] | M[3])) return;
        u64 msk = (row & 2) ? ((row & 1) ? M[3] : M[2])
                            : ((row & 1) ? M[1] : M[0]);
        int cnt = (int)__popcll((msk >> ((row >> 2) << 4)) & 0xFFFFull);
        int cmax = cnt;
        #pragma unroll
        for (int o = 1; o < 16; o <<= 1)
          cmax = max(cmax, __shfl_xor(cmax, o));
        for (int j = 0; j < cmax; ++j) {
          u64 cand = Q[wv][row][j];
          if (j >= cnt) cand = 0;                    // never inserts
          u64 m01 = slot[0] < slot[1] ? slot[0] : slot[1];
          u64 m23 = slot[2] < slot[3] ? slot[2] : slot[3];
          u64 lmin = m01 < m23 ? m01 : m23;
          u64 g = sx64(lmin, 16); if (g < lmin) lmin = g;
          g = sx64(lmin, 32); u64 gmin = (g < lmin) ? g : lmin;
          bool ins = cand > gmin;
          #pragma unroll
          for (int s2 = 0; s2 < 4; ++s2)
            if (ins && slot[s2] == gmin) slot[s2] = cand;
        }
        // refresh this row's 16th value (group min) for producer thresholds
        u64 m01 = slot[0] < slot[1] ? slot[0] : slot[1];
        u64 m23 = slot[2] < slot[3] ? slot[2] : slot[3];
        u64 lmin = m01 < m23 ? m01 : m23;
        u64 g = sx64(lmin, 16); if (g < lmin) lmin = g;
        g = sx64(lmin, 32); if (g < lmin) lmin = g;
        myth = unsortf((u32)(lmin >> 32));
      };

      u64 M0[4], M1[4];
      produce(acc0, th0, M0);
      drain(M0, slot0, myth0);
      produce(acc1, th1, M1);
      drain(M1, slot1, myth1);
      if (M0[0] | M0[1] | M0[2] | M0[3]) {
        #pragma unroll
        for (int r = 0; r < 4; ++r) th0[r] = __shfl(myth0, q4 + r);
      }
      if (M1[0] | M1[1] | M1[2] | M1[3]) {
        #pragma unroll
        for (int r = 0; r < 4; ++r) th1[r] = __shfl(myth1, q4 + r);
      }
    }
  }

  // writeout: lane (sg,row) holds slots sg*4+s of rows rowbase+row (+16)
  {
    const int sg = lane >> 4;
    const int r0 = rowbase + row, r1 = rowbase + 16 + row;
    #pragma unroll
    for (int s = 0; s < 4; ++s) {
      u64 e0 = slot0[s], e1 = slot1[s];
      int col = p * 16 + sg * 4 + s;
      Rpv[(size_t)r0 * 128 + col] = unsortf((u32)(e0 >> 32));
      Rpi[(size_t)r0 * 128 + col] = (int)(~(u32)e0);
      Rpv[(size_t)r1 * 128 + col] = unsortf((u32)(e1 >> 32));
      Rpi[(size_t)r1 * 128 + col] = (int)(~(u32)e1);
    }
  }
}

// ---------------------------------------------------------------------------
// K2b: exact top-16 of the 128 partition candidates per row (rank counting).
// grid = 2048 blocks x 4 waves (1 row/wave).
// ---------------------------------------------------------------------------
__global__ __launch_bounds__(256) void k2_merge(
    const float* __restrict__ Rpv, const int* __restrict__ Rpi,
    int* __restrict__ Ridx) {
  const int t = threadIdx.x, lane = t & 63, wv = t >> 6;
  const int row = blockIdx.x * 4 + wv;
  const float va = Rpv[(size_t)row * 128 + lane];
  const int   ea = Rpi[(size_t)row * 128 + lane];
  const float vb = Rpv[(size_t)row * 128 + 64 + lane];
  const int   eb = Rpi[(size_t)row * 128 + 64 + lane];
  int ca = 0, cb = 0;
  for (int i = 0; i < 64; ++i) {
    float ov = __shfl(va, i); int oi = __shfl(ea, i);
    ca += (ov > va || (ov == va && oi < ea));
    cb += (ov > vb || (ov == vb && oi < eb));
  }
  for (int i = 0; i < 64; ++i) {
    float ov = __shfl(vb, i); int oi = __shfl(eb, i);
    ca += (ov > va || (ov == va && oi < ea));
    cb += (ov > vb || (ov == vb && oi < eb));
  }
  if (ca < 16) Ridx[(size_t)row * 16 + ca] = ea;
  if (cb < 16) Ridx[(size_t)row * 16 + cb] = eb;
}

// ---------------------------------------------------------------------------
// K3: batched-span GCN on the MATRIX CORES. grid = 2048 x 256 (4 waves);
// 4 spans/block (32 node rows). fp64 re-rank of 16 candidates (from exact
// fp32 out1 + ent) -> top-8. Star-mix commutes with the GEMM:
//   out = A·relu(A·X·W1 + b1)·W2 + b2,  A·(X·W) = (A·X)·W
// so both GEMMs run on RAW rows via bf16 MFMA (fp32 accum), and the mix is
// applied column-locally on the fp32 MFMA output.
// LDS: Abf (bf16 A-operand, 17.4 KB) + UN union{re-rank scratch | W-slab
// transposed bf16 (20.5 KB) | fp32 C-out (34.3 KB)} -> ~52 KB, 3 blocks/CU.
// MFMA fragment conventions identical to k2 (proven).
// ---------------------------------------------------------------------------
__global__ __launch_bounds__(256, 3) void k3_gcn(
    const float* __restrict__ out1, const float* __restrict__ ent,
    const int* __restrict__ Ridx,
    const float* __restrict__ W1, const float* __restrict__ b1,
    const float* __restrict__ W2, const float* __restrict__ b2,
    float* __restrict__ out2, int ne) {
  __shared__ __align__(16) char UN[34560];
  __shared__ __align__(16) u16 Abf[32][272];   // A operand bf16 (X, then H)
  __shared__ int cidx[4][16];
  __shared__ int chos[4][8];
  const int t = threadIdx.x;
  const int lane = t & 63, wv = t >> 6;
  const int m = lane & 15, q = lane >> 4;
  const int n0 = blockIdx.x * 4;

  // ---- phase 1: re-rank (fp64) -> chos[4][8]. scratch lives in UN. ----
  {
    float  (*SPR)[256] = (float (*)[256])UN;            // 4 KB
    double (*dpart)[4] = (double (*)[4])(UN + 4096);    // 2 KB
    double (*sims)[16] = (double (*)[16])(UN + 6144);   // 0.5 KB
    #pragma unroll
    for (int g = 0; g < 4; ++g)
      SPR[g][t] = out1[(size_t)(n0 + g) * 256 + t];
    if (t < 64) {
      int g = t >> 4, j = t & 15;
      int c = Ridx[(size_t)(n0 + g) * 16 + j];
      if ((unsigned)c >= (unsigned)ne) c = 0;   // defensive
      cidx[g][j] = c;
    }
    __syncthreads();

    {
      const int pr = t >> 2, sub = t & 3;
      const int g = pr >> 4, j = pr & 15;
      const float* er = ent + (size_t)cidx[g][j] * 256 + sub * 64;
      const float* sr = &SPR[g][sub * 64];
      double s = 0.0;
      #pragma unroll
      for (int i = 0; i < 64; i += 4) {
        float4 e4 = *(const float4*)&er[i];
        float4 s4 = *(const float4*)&sr[i];
        s += (double)e4.x * (double)s4.x;
        s += (double)e4.y * (double)s4.y;
        s += (double)e4.z * (double)s4.z;
        s += (double)e4.w * (double)s4.w;
      }
      dpart[pr][sub] = s;
    }
    __syncthreads();
    if (t < 64) {
      int g = t >> 4, j = t & 15;
      sims[g][j] = dpart[t][0] + dpart[t][1] + dpart[t][2] + dpart[t][3];
    }
    __syncthreads();
    if (t < 4) {
      unsigned used = 0;
      for (int o = 0; o < 8; ++o) {
        int best = -1; double bv = 0.0; int bi = 0;
        for (int j = 0; j < 16; ++j) {
          if (used & (1u << j)) continue;
          if (best < 0 || sims[t][j] > bv || (sims[t][j] == bv && cidx[t][j] < bi)) {
            best = j; bv = sims[t][j]; bi = cidx[t][j];
          }
        }
        used |= (1u << best);
        chos[t][o] = cidx[t][best];
      }
    }
    __syncthreads();
  }

  // ---- phase 2: gather 32 ent rows -> bf16 -> Abf (raw X, no mix) ----
  {
    const int r = t >> 3, cb = t & 7;
    const float* src = ent + (size_t)chos[r >> 3][r & 7] * 256 + cb * 32;
    u32 pk[16];
    #pragma unroll
    for (int i = 0; i < 8; ++i) {
      float4 v = *(const float4*)&src[i * 4];
      pk[2 * i]     = (u32)f2bf(v.x) | ((u32)f2bf(v.y) << 16);
      pk[2 * i + 1] = (u32)f2bf(v.z) | ((u32)f2bf(v.w) << 16);
    }
    uint4* dst = (uint4*)&Abf[r][cb * 32];
    #pragma unroll
    for (int i = 0; i < 4; ++i)
      dst[i] = make_uint4(pk[4 * i], pk[4 * i + 1], pk[4 * i + 2], pk[4 * i + 3]);
  }

  // ---- MFMA GEMM: C(32x256) = Abf(32x256) @ W(256x256), result -> Cl(UN)
  auto run_gemm = [&](const float* __restrict__ Wg) {
    f32x4 acc[2][4];
    #pragma unroll
    for (int mt = 0; mt < 2; ++mt)
      #pragma unroll
      for (int nt = 0; nt < 4; ++nt)
        acc[mt][nt] = (f32x4){0.f, 0.f, 0.f, 0.f};

    for (int s = 0; s < 8; ++s) {
      __syncthreads();               // UN free (prev reads done / Abf ready)
      {  // stage W-slab s: rows s*32..+32, transposed bf16. thread t = col t.
        const float* src = Wg + (size_t)(s * 32) * 256 + t;
        u32 pk[16];
        #pragma unroll
        for (int i = 0; i < 16; ++i) {
          float lo = src[(size_t)(2 * i) * 256];
          float hi = src[(size_t)(2 * i + 1) * 256];
          pk[i] = (u32)f2bf(lo) | ((u32)f2bf(hi) << 16);
        }
        uint4* dst = (uint4*)(UN + t * 80);    // Bt[col][40 u16], 80B rows
        #pragma unroll
        for (int i = 0; i < 4; ++i)
          dst[i] = make_uint4(pk[4 * i], pk[4 * i + 1], pk[4 * i + 2], pk[4 * i + 3]);
      }
      __syncthreads();               // Bt ready
      #pragma unroll
      for (int mt = 0; mt < 2; ++mt) {
        bf16x8 af = *(const bf16x8*)((const char*)Abf
                       + (mt * 16 + m) * 544 + s * 64 + q * 16);
        #pragma unroll
        for (int nt = 0; nt < 4; ++nt) {
          const int col = wv * 64 + nt * 16 + m;
          bf16x8 bf = *(const bf16x8*)(UN + col * 80 + q * 16);
          acc[mt][nt] = __builtin_amdgcn_mfma_f32_16x16x32_bf16(
              af, bf, acc[mt][nt], 0, 0, 0);
        }
      }
    }
    __syncthreads();                 // all MFMA reads of UN done -> Cl view
    #pragma unroll
    for (int mt = 0; mt < 2; ++mt)
      #pragma unroll
      for (int nt = 0; nt < 4; ++nt)
        #pragma unroll
        for (int r = 0; r < 4; ++r)
          *(float*)(UN + (((mt * 16 + q * 4 + r) * 268)
                          + (wv * 64 + nt * 16 + m)) * 4) = acc[mt][nt][r];
    __syncthreads();                 // Cl ready
  };

  // ---- GEMM1 + mix + b1 + relu -> H (bf16) back into Abf ----
  run_gemm(W1);
  {
    const float bb = b1[t];
    #pragma unroll
    for (int g = 0; g < 4; ++g) {
      float v[8];
      #pragma unroll
      for (int j = 0; j < 8; ++j)
        v[j] = *(const float*)(UN + ((g * 8 + j) * 268 + t) * 4);
      float ssum = 0.f;
      #pragma unroll
      for (int j = 1; j < 8; ++j) ssum += v[j];
      Abf[g * 8][t] = f2bf(fmaxf(v[0] * 0.125f + ssum * 0.25f + bb, 0.f));
      #pragma unroll
      for (int j = 1; j < 8; ++j)
        Abf[g * 8 + j][t] = f2bf(fmaxf(v[0] * 0.25f + v[j] * 0.5f + bb, 0.f));
    }
  }
  // (run_gemm's leading barrier separates these Cl reads / Abf writes
  //  from GEMM2's staging writes / Abf reads)

  // ---- GEMM2 + mix + b2 -> out2 ----
  run_gemm(W2);
  {
    const float bb = b2[t];
    #pragma unroll
    for (int g = 0; g < 4; ++g) {
      float v[8];
      #pragma unroll
      for (int j = 0; j < 8; ++j)
        v[j] = *(const float*)(UN + ((g * 8 + j) * 268 + t) * 4);
      float ssum = 0.f;
      #pragma unroll
      for (int j = 1; j < 8; ++j) ssum += v[j];
      float* ob = out2 + (size_t)(n0 + g) * 2048 + t;
      ob[0] = v[0] * 0.125f + ssum * 0.25f + bb;
      #pragma unroll
      for (int j = 1; j < 8; ++j)
        ob[(size_t)j * 256] = v[0] * 0.25f + v[j] * 0.5f + bb;
    }
  }
}

// ---------------------------------------------------------------------------
extern "C" void kernel_launch(void* const* d_in, const int* in_sizes, int n_in,
                              void* d_out, int out_size, void* d_ws, size_t ws_size,
                              hipStream_t stream) {
  const float* emb = (const float*)d_in[0];
  const float* ent = (const float*)d_in[1];
  const float* Wsp = (const float*)d_in[2];
  const float* bsp = (const float*)d_in[3];
  const float* W1  = (const float*)d_in[4];
  const float* b1  = (const float*)d_in[5];
  const float* W2  = (const float*)d_in[6];
  const float* b2  = (const float*)d_in[7];
  const int ne = in_sizes[1] / 256;   // 50000

  float* out  = (float*)d_out;
  float* out0 = out;                        // cls: 1024
  float* out1 = out + 1024;                 // span_repr: 8192*256
  float* out2 = out + 1024 + 2097152;       // subgraph_out: 64 MB region

  // scratch overlays on out2 (consumed before k3 overwrites; strict order):
  char* ov = (char*)out2;
  u16*   entbf  = (u16*)(ov);                     // 25.6 MB bf16 entity table
  u16*   spanbf = (u16*)(ov + 33554432);          //  4 MB bf16 span matrix
  float* Rpv    = (float*)(ov + 41943040);        //  4 MB partial topk vals
  int*   Rpi    = (int*)  (ov + 50331648);        //  4 MB partial topk idx
  int*   Ridx   = (int*)d_ws;                     // 512 KB final top-16 idx

  hipLaunchKernelGGL(k0_cvt, dim3((ne * 64 + 255) / 256), dim3(256), 0, stream,
                     ent, entbf, ne * 64);
  hipLaunchKernelGGL(k1_span, dim3(1024), dim3(256), 0, stream,
                     emb, Wsp, bsp, out0, out1, spanbf);
  hipLaunchKernelGGL(k2_mfma, dim3(512), dim3(256), 0, stream,
                     spanbf, entbf, ne, Rpv, Rpi);
  hipLaunchKernelGGL(k2_merge, dim3(2048), dim3(256), 0, stream,
                     Rpv, Rpi, Ridx);
  hipLaunchKernelGGL(k3_gcn, dim3(2048), dim3(256), 0, stream,
                     out1, ent, Ridx, W1, b1, W2, b2, out2, ne);
}